// Round 1
// baseline (1246.782 us; speedup 1.0000x reference)
//
#include <hip/hip_runtime.h>

#define NN 100000
#define NE 1600000
#define HC 256

__device__ __forceinline__ float4 ld4(const float* p) { return *(const float4*)p; }
__device__ __forceinline__ void st4(float* p, float4 v) { *(float4*)p = v; }

// ---------------- GEMM1: h1 = x @ W1  (+ fused attention logits) -------------
__global__ void k_gemm1(const float* __restrict__ x, const float* __restrict__ W1,
                        const float* __restrict__ a_s, const float* __restrict__ a_d,
                        float* __restrict__ h, float* __restrict__ al_s, float* __restrict__ al_d) {
    int wid = (blockIdx.x * blockDim.x + threadIdx.x) >> 6;   // one wave per node
    int lane = threadIdx.x & 63;
    if (wid >= NN) return;
    float x0 = x[wid * 3 + 0], x1 = x[wid * 3 + 1], x2 = x[wid * 3 + 2];
    int c = lane << 2;
    float4 w0 = ld4(W1 + c), w1 = ld4(W1 + 256 + c), w2 = ld4(W1 + 512 + c);
    float4 hv;
    hv.x = x0 * w0.x + x1 * w1.x + x2 * w2.x;
    hv.y = x0 * w0.y + x1 * w1.y + x2 * w2.y;
    hv.z = x0 * w0.z + x1 * w1.z + x2 * w2.z;
    hv.w = x0 * w0.w + x1 * w1.w + x2 * w2.w;
    st4(h + (size_t)wid * HC + c, hv);
    float4 as = ld4(a_s + c), ad = ld4(a_d + c);
    float ps = hv.x * as.x + hv.y * as.y + hv.z * as.z + hv.w * as.w;
    float pd = hv.x * ad.x + hv.y * ad.y + hv.z * ad.z + hv.w * ad.w;
    #pragma unroll
    for (int m = 1; m < 16; m <<= 1) { ps += __shfl_xor(ps, m, 64); pd += __shfl_xor(pd, m, 64); }
    if ((lane & 15) == 0) {
        al_s[wid * 4 + (lane >> 4)] = ps;
        al_d[wid * 4 + (lane >> 4)] = pd;
    }
}

// ---------------- CSR build --------------------------------------------------
__global__ void k_count(const int* __restrict__ dst, int* __restrict__ counts) {
    int i = blockIdx.x * blockDim.x + threadIdx.x;
    if (i < NE) atomicAdd(&counts[dst[i]], 1);
}

__global__ void k_scan(const int* __restrict__ counts, int* __restrict__ offs) {
    __shared__ int sh[1024];
    __shared__ int carry_sh;
    int t = threadIdx.x;
    if (t == 0) carry_sh = 0;
    __syncthreads();
    for (int base = 0; base < NN; base += 1024) {
        int v = (base + t < NN) ? counts[base + t] : 0;
        sh[t] = v;
        __syncthreads();
        for (int off = 1; off < 1024; off <<= 1) {
            int y = (t >= off) ? sh[t - off] : 0;
            __syncthreads();
            sh[t] += y;
            __syncthreads();
        }
        int incl = sh[t];
        int carry = carry_sh;
        if (base + t < NN) offs[base + t] = carry + incl - v;
        __syncthreads();
        if (t == 1023) carry_sh = carry + sh[1023];
        __syncthreads();
    }
    if (t == 0) offs[NN] = carry_sh;
}

__global__ void k_copy(const int* __restrict__ a, int* __restrict__ b, int n) {
    int i = blockIdx.x * blockDim.x + threadIdx.x;
    if (i < n) b[i] = a[i];
}

__global__ void k_scatter(const int* __restrict__ src, const int* __restrict__ dst,
                          int* __restrict__ cursor, int* __restrict__ csr) {
    int i = blockIdx.x * blockDim.x + threadIdx.x;
    if (i < NE) {
        int d = dst[i];
        int p = atomicAdd(&cursor[d], 1);
        csr[p] = src[i];
    }
}

// ---------------- per-dst online-softmax aggregation -------------------------
// one wave per destination node; self-loop initializes the online softmax.
template <int FUSE_FC>
__global__ void k_agg(const float* __restrict__ h, const float* __restrict__ al_s,
                      const float* __restrict__ al_d, const int* __restrict__ offs,
                      const int* __restrict__ csr, const float* __restrict__ bias,
                      const float* __restrict__ fcw, const float* __restrict__ fcb,
                      float* __restrict__ out) {
    int d = (blockIdx.x * blockDim.x + threadIdx.x) >> 6;
    int lane = threadIdx.x & 63;
    if (d >= NN) return;
    int head = lane >> 4;
    int c = lane << 2;
    float ald = al_d[d * 4 + head];
    // self loop first
    float e0 = al_s[d * 4 + head] + ald;
    e0 = e0 > 0.f ? e0 : 0.2f * e0;
    float m = e0, s = 1.f;
    float4 acc = ld4(h + (size_t)d * HC + c);
    int beg = offs[d], end = offs[d + 1];
    for (int i = beg; i < end; ++i) {
        int sn = csr[i];
        float ev = al_s[sn * 4 + head] + ald;
        ev = ev > 0.f ? ev : 0.2f * ev;
        float4 hv = ld4(h + (size_t)sn * HC + c);
        float mn = fmaxf(m, ev);
        float cs = __expf(m - mn);
        float p = __expf(ev - mn);
        s = s * cs + p;
        acc.x = acc.x * cs + p * hv.x;
        acc.y = acc.y * cs + p * hv.y;
        acc.z = acc.z * cs + p * hv.z;
        acc.w = acc.w * cs + p * hv.w;
        m = mn;
    }
    float inv = 1.f / (s + 1e-16f);
    float4 bv = ld4(bias + c);
    float4 o;
    o.x = fmaxf(acc.x * inv + bv.x, 0.f);
    o.y = fmaxf(acc.y * inv + bv.y, 0.f);
    o.z = fmaxf(acc.z * inv + bv.z, 0.f);
    o.w = fmaxf(acc.w * inv + bv.w, 0.f);
    if (!FUSE_FC) {
        st4(out + (size_t)d * HC + c, o);
    } else {
        float p0 = o.x * fcw[(c + 0) * 2 + 0] + o.y * fcw[(c + 1) * 2 + 0] +
                   o.z * fcw[(c + 2) * 2 + 0] + o.w * fcw[(c + 3) * 2 + 0];
        float p1 = o.x * fcw[(c + 0) * 2 + 1] + o.y * fcw[(c + 1) * 2 + 1] +
                   o.z * fcw[(c + 2) * 2 + 1] + o.w * fcw[(c + 3) * 2 + 1];
        #pragma unroll
        for (int mm = 1; mm < 64; mm <<= 1) {
            p0 += __shfl_xor(p0, mm, 64);
            p1 += __shfl_xor(p1, mm, 64);
        }
        if (lane == 0) {
            out[d * 2 + 0] = p0 + fcb[0];
            out[d * 2 + 1] = p1 + fcb[1];
        }
    }
}

// ---------------- GEMM2: h2 = z1 @ W2 (+ fused attention logits) -------------
#define BM2 32
#define BK2 32
__global__ __launch_bounds__(256) void k_gemm2(const float* __restrict__ z, const float* __restrict__ W2,
                                               const float* __restrict__ a_s, const float* __restrict__ a_d,
                                               float* __restrict__ h2, float* __restrict__ al_s,
                                               float* __restrict__ al_d) {
    __shared__ float zt[BM2][BK2 + 4];   // stride 36 dwords = 144B, 16B-aligned rows
    __shared__ float wt[BK2][HC];
    int t = threadIdx.x;
    int lane = t & 63, w = t >> 6;
    int row0 = blockIdx.x * BM2;
    float acc[8][4];
    #pragma unroll
    for (int i = 0; i < 8; ++i)
        #pragma unroll
        for (int j = 0; j < 4; ++j) acc[i][j] = 0.f;

    for (int k0 = 0; k0 < HC; k0 += BK2) {
        {   // stage z tile: 32 rows x 32 cols, one float4 per thread
            int r = t >> 3, cc = (t & 7) << 2;
            int gr = row0 + r;
            float4 v = make_float4(0.f, 0.f, 0.f, 0.f);
            if (gr < NN) v = ld4(z + (size_t)gr * HC + k0 + cc);
            st4(&zt[r][cc], v);
        }
        #pragma unroll
        for (int rr = 0; rr < 8; ++rr) {   // stage W2 tile: 32 x 256
            int idx = rr * 256 + t;
            int r = idx >> 6, c4 = (idx & 63) << 2;
            st4(&wt[r][c4], ld4(W2 + (size_t)(k0 + r) * HC + c4));
        }
        __syncthreads();
        int r0 = w * 8;
        #pragma unroll
        for (int kk4 = 0; kk4 < BK2 / 4; ++kk4) {
            float4 wv[4];
            #pragma unroll
            for (int j = 0; j < 4; ++j) wv[j] = ld4(&wt[kk4 * 4 + j][lane << 2]);
            #pragma unroll
            for (int i = 0; i < 8; ++i) {
                float4 zq = ld4(&zt[r0 + i][kk4 << 2]);
                acc[i][0] += zq.x * wv[0].x + zq.y * wv[1].x + zq.z * wv[2].x + zq.w * wv[3].x;
                acc[i][1] += zq.x * wv[0].y + zq.y * wv[1].y + zq.z * wv[2].y + zq.w * wv[3].y;
                acc[i][2] += zq.x * wv[0].z + zq.y * wv[1].z + zq.z * wv[2].z + zq.w * wv[3].z;
                acc[i][3] += zq.x * wv[0].w + zq.y * wv[1].w + zq.z * wv[2].w + zq.w * wv[3].w;
            }
        }
        __syncthreads();
    }
    int c = lane << 2;
    float4 asv = ld4(a_s + c), adv = ld4(a_d + c);
    #pragma unroll
    for (int i = 0; i < 8; ++i) {
        int gr = row0 + w * 8 + i;
        if (gr < NN) {
            float4 o = make_float4(acc[i][0], acc[i][1], acc[i][2], acc[i][3]);
            st4(h2 + (size_t)gr * HC + c, o);
            float ps = o.x * asv.x + o.y * asv.y + o.z * asv.z + o.w * asv.w;
            float pd = o.x * adv.x + o.y * adv.y + o.z * adv.z + o.w * adv.w;
            #pragma unroll
            for (int mm = 1; mm < 16; mm <<= 1) { ps += __shfl_xor(ps, mm, 64); pd += __shfl_xor(pd, mm, 64); }
            if ((lane & 15) == 0) {
                al_s[gr * 4 + (lane >> 4)] = ps;
                al_d[gr * 4 + (lane >> 4)] = pd;
            }
        }
    }
}

extern "C" void kernel_launch(void* const* d_in, const int* in_sizes, int n_in,
                              void* d_out, int out_size, void* d_ws, size_t ws_size,
                              hipStream_t stream) {
    const float* x   = (const float*)d_in[0];
    const int*   ei  = (const int*)d_in[1];
    const float* W1  = (const float*)d_in[2];
    const float* as1 = (const float*)d_in[3];
    const float* ad1 = (const float*)d_in[4];
    const float* b1  = (const float*)d_in[5];
    const float* W2  = (const float*)d_in[6];
    const float* as2 = (const float*)d_in[7];
    const float* ad2 = (const float*)d_in[8];
    const float* b2  = (const float*)d_in[9];
    const float* fcw = (const float*)d_in[10];
    const float* fcb = (const float*)d_in[11];
    float* out = (float*)d_out;

    char* p = (char*)d_ws;
    float* bufA = (float*)p; p += (size_t)NN * HC * 4;    // h1, later h2
    float* bufB = (float*)p; p += (size_t)NN * HC * 4;    // z1
    float* alS  = (float*)p; p += (size_t)NN * 4 * 4;
    float* alD  = (float*)p; p += (size_t)NN * 4 * 4;
    int* counts = (int*)p;   p += (size_t)NN * 4;
    int* offs   = (int*)p;   p += (size_t)(NN + 1) * 4;
    int* cursor = (int*)p;   p += (size_t)NN * 4;
    int* csr    = (int*)p;   p += (size_t)NE * 4;

    const int* e_src = ei;
    const int* e_dst = ei + NE;

    hipMemsetAsync(counts, 0, NN * sizeof(int), stream);
    k_count<<<(NE + 255) / 256, 256, 0, stream>>>(e_dst, counts);
    k_scan<<<1, 1024, 0, stream>>>(counts, offs);
    k_copy<<<(NN + 255) / 256, 256, 0, stream>>>(offs, cursor, NN);
    k_scatter<<<(NE + 255) / 256, 256, 0, stream>>>(e_src, e_dst, cursor, csr);

    k_gemm1<<<(NN + 3) / 4, 256, 0, stream>>>(x, W1, as1, ad1, bufA, alS, alD);
    k_agg<0><<<(NN + 3) / 4, 256, 0, stream>>>(bufA, alS, alD, offs, csr, b1, nullptr, nullptr, bufB);
    k_gemm2<<<(NN + BM2 - 1) / BM2, 256, 0, stream>>>(bufB, W2, as2, ad2, bufA, alS, alD);
    k_agg<1><<<(NN + 3) / 4, 256, 0, stream>>>(bufA, alS, alD, offs, csr, b2, fcw, fcb, out);
}

// Round 2
// 807.948 us; speedup vs baseline: 1.5431x; 1.5431x over previous
//
#include <hip/hip_runtime.h>

#define NN 100000
#define NE 1600000
#define HC 256
#define NB_SCAN 98   // ceil(NN/1024)

typedef __attribute__((ext_vector_type(8))) short short8;
typedef __attribute__((ext_vector_type(4))) float f32x4;

__device__ __forceinline__ float4 ld4(const float* p) { return *(const float4*)p; }
__device__ __forceinline__ void st4(float* p, float4 v) { *(float4*)p = v; }
__device__ __forceinline__ unsigned short f2bf(float f) {
    unsigned u = __float_as_uint(f);
    return (unsigned short)((u + 0x7fffu + ((u >> 16) & 1u)) >> 16);
}
__device__ __forceinline__ float bf2f(unsigned short h) { return __uint_as_float(((unsigned)h) << 16); }

// ---------------- GEMM1: h1 = x @ W1  (+ fused attention logits) -------------
__global__ void k_gemm1(const float* __restrict__ x, const float* __restrict__ W1,
                        const float* __restrict__ a_s, const float* __restrict__ a_d,
                        float* __restrict__ h, float* __restrict__ al_s, float* __restrict__ al_d) {
    int wid = (blockIdx.x * blockDim.x + threadIdx.x) >> 6;
    int lane = threadIdx.x & 63;
    if (wid >= NN) return;
    float x0 = x[wid * 3 + 0], x1 = x[wid * 3 + 1], x2 = x[wid * 3 + 2];
    int c = lane << 2;
    float4 w0 = ld4(W1 + c), w1 = ld4(W1 + 256 + c), w2 = ld4(W1 + 512 + c);
    float4 hv;
    hv.x = x0 * w0.x + x1 * w1.x + x2 * w2.x;
    hv.y = x0 * w0.y + x1 * w1.y + x2 * w2.y;
    hv.z = x0 * w0.z + x1 * w1.z + x2 * w2.z;
    hv.w = x0 * w0.w + x1 * w1.w + x2 * w2.w;
    st4(h + (size_t)wid * HC + c, hv);
    float4 as = ld4(a_s + c), ad = ld4(a_d + c);
    float ps = hv.x * as.x + hv.y * as.y + hv.z * as.z + hv.w * as.w;
    float pd = hv.x * ad.x + hv.y * ad.y + hv.z * ad.z + hv.w * ad.w;
    #pragma unroll
    for (int m = 1; m < 16; m <<= 1) { ps += __shfl_xor(ps, m, 64); pd += __shfl_xor(pd, m, 64); }
    if ((lane & 15) == 0) {
        al_s[wid * 4 + (lane >> 4)] = ps;
        al_d[wid * 4 + (lane >> 4)] = pd;
    }
}

// ---------------- CSR build --------------------------------------------------
__global__ void k_count(const int* __restrict__ dst, int* __restrict__ counts) {
    int i = blockIdx.x * blockDim.x + threadIdx.x;
    if (i < NE) atomicAdd(&counts[dst[i]], 1);
}

__global__ void k_scan1(const int* __restrict__ counts, int* __restrict__ offs,
                        int* __restrict__ partials) {
    __shared__ int sh[1024];
    int b = blockIdx.x, t = threadIdx.x, i = b * 1024 + t;
    int v = (i < NN) ? counts[i] : 0;
    sh[t] = v;
    __syncthreads();
    for (int o = 1; o < 1024; o <<= 1) {
        int y = (t >= o) ? sh[t - o] : 0;
        __syncthreads();
        sh[t] += y;
        __syncthreads();
    }
    if (i < NN) offs[i] = sh[t] - v;
    if (t == 1023) partials[b] = sh[t];
}

__global__ void k_scan2(const int* __restrict__ partials, int* __restrict__ carries) {
    __shared__ int sh[128];
    int t = threadIdx.x;
    int v = (t < NB_SCAN) ? partials[t] : 0;
    sh[t] = v;
    __syncthreads();
    for (int o = 1; o < 128; o <<= 1) {
        int y = (t >= o) ? sh[t - o] : 0;
        __syncthreads();
        sh[t] += y;
        __syncthreads();
    }
    if (t < NB_SCAN) carries[t] = sh[t] - v;
}

__global__ void k_scan3(const int* __restrict__ carries, int* __restrict__ offs,
                        int* __restrict__ cursor) {
    int b = blockIdx.x, i = b * 1024 + threadIdx.x;
    if (i < NN) {
        int val = offs[i] + carries[b];
        offs[i] = val;
        cursor[i] = val;
    }
    if (i == 0) offs[NN] = NE;
}

__global__ void k_scatter(const int* __restrict__ src, const int* __restrict__ dst,
                          int* __restrict__ cursor, int* __restrict__ csr) {
    int i = blockIdx.x * blockDim.x + threadIdx.x;
    if (i < NE) {
        int d = dst[i];
        int p = atomicAdd(&cursor[d], 1);
        csr[p] = src[i];
    }
}

// ---------------- B' prep: Bt[c][vk], vk: 0-255=hi(W2), 256-511=lo(W2), 512-767=hi(W2)
__global__ void k_prep_bt(const float* __restrict__ W2, unsigned short* __restrict__ Bt) {
    int vk = blockIdx.x, c = threadIdx.x;
    float v = W2[(size_t)(vk & 255) * HC + c];
    unsigned short hi = f2bf(v);
    unsigned short o = (vk < 256 || vk >= 512) ? hi : f2bf(v - bf2f(hi));
    Bt[(size_t)c * 768 + vk] = o;
}

// ---------------- per-dst online-softmax aggregation -------------------------
// MODE 0: write z as bf16 hi|lo (cols 0-255 hi, 256-511 lo).  MODE 1: fused fc.
template <int MODE>
__global__ void k_agg(const float* __restrict__ h, const float* __restrict__ al_s,
                      const float* __restrict__ al_d, const int* __restrict__ offs,
                      const int* __restrict__ csr, const float* __restrict__ bias,
                      const float* __restrict__ fcw, const float* __restrict__ fcb,
                      float* __restrict__ outF, unsigned short* __restrict__ zhl) {
    int d = (blockIdx.x * blockDim.x + threadIdx.x) >> 6;
    int lane = threadIdx.x & 63;
    if (d >= NN) return;
    int head = lane >> 4;
    int c = lane << 2;
    float ald = al_d[d * 4 + head];
    float e0 = al_s[d * 4 + head] + ald;
    e0 = e0 > 0.f ? e0 : 0.2f * e0;
    float m = e0, s = 1.f;
    float4 acc = ld4(h + (size_t)d * HC + c);
    int beg = offs[d], end = offs[d + 1];
    if (beg < end) {
        int sn = csr[beg];
        float asv = al_s[sn * 4 + head];
        float4 hv = ld4(h + (size_t)sn * HC + c);
        for (int i = beg; i < end; ++i) {
            int i2 = i + 1;
            int sn2 = (i2 < end) ? csr[i2] : sn;
            float as2 = al_s[sn2 * 4 + head];          // prefetch next edge
            float4 hv2 = ld4(h + (size_t)sn2 * HC + c);
            float ev = asv + ald;
            ev = ev > 0.f ? ev : 0.2f * ev;
            float mn = fmaxf(m, ev);
            float cs = __expf(m - mn);
            float p = __expf(ev - mn);
            s = s * cs + p;
            acc.x = acc.x * cs + p * hv.x;
            acc.y = acc.y * cs + p * hv.y;
            acc.z = acc.z * cs + p * hv.z;
            acc.w = acc.w * cs + p * hv.w;
            m = mn;
            sn = sn2; asv = as2; hv = hv2;
        }
    }
    float inv = 1.f / (s + 1e-16f);
    float4 bv = ld4(bias + c);
    float4 o;
    o.x = fmaxf(acc.x * inv + bv.x, 0.f);
    o.y = fmaxf(acc.y * inv + bv.y, 0.f);
    o.z = fmaxf(acc.z * inv + bv.z, 0.f);
    o.w = fmaxf(acc.w * inv + bv.w, 0.f);
    if (MODE == 0) {
        ushort4 hi, lo;
        hi.x = f2bf(o.x); lo.x = f2bf(o.x - bf2f(hi.x));
        hi.y = f2bf(o.y); lo.y = f2bf(o.y - bf2f(hi.y));
        hi.z = f2bf(o.z); lo.z = f2bf(o.z - bf2f(hi.z));
        hi.w = f2bf(o.w); lo.w = f2bf(o.w - bf2f(hi.w));
        *(ushort4*)(zhl + (size_t)d * 512 + c) = hi;
        *(ushort4*)(zhl + (size_t)d * 512 + 256 + c) = lo;
    } else {
        float p0 = o.x * fcw[(c + 0) * 2 + 0] + o.y * fcw[(c + 1) * 2 + 0] +
                   o.z * fcw[(c + 2) * 2 + 0] + o.w * fcw[(c + 3) * 2 + 0];
        float p1 = o.x * fcw[(c + 0) * 2 + 1] + o.y * fcw[(c + 1) * 2 + 1] +
                   o.z * fcw[(c + 2) * 2 + 1] + o.w * fcw[(c + 3) * 2 + 1];
        #pragma unroll
        for (int mm = 1; mm < 64; mm <<= 1) {
            p0 += __shfl_xor(p0, mm, 64);
            p1 += __shfl_xor(p1, mm, 64);
        }
        if (lane == 0) {
            outF[d * 2 + 0] = p0 + fcb[0];
            outF[d * 2 + 1] = p1 + fcb[1];
        }
    }
}

// ---------------- GEMM2 via bf16 MFMA (hi/lo split), fused logits ------------
// Block: 512 thr (8 waves, 2M x 4N), tile M=128 N=256, virtual K=768, BK=64.
__global__ __launch_bounds__(512) void k_gemm2_mfma(
    const unsigned short* __restrict__ zhl, const unsigned short* __restrict__ Bt,
    const float* __restrict__ a_s, const float* __restrict__ a_d,
    float* __restrict__ h2, float* __restrict__ al_s, float* __restrict__ al_d) {
    __shared__ __align__(16) unsigned short As[128 * 64];
    __shared__ __align__(16) unsigned short Bs[256 * 64];
    int t = threadIdx.x;
    int l = t & 63, w = t >> 6;
    int wm = w >> 2, wn = w & 3;
    int lr = l & 15, lk = l >> 4;
    int row0 = blockIdx.x * 128;

    f32x4 acc[4][4];
    f32x4 z4 = {0.f, 0.f, 0.f, 0.f};
    #pragma unroll
    for (int i = 0; i < 4; ++i)
        #pragma unroll
        for (int j = 0; j < 4; ++j) acc[i][j] = z4;

    int sa_row = t >> 2, sa_q = t & 3;           // A: 32B per thread
    const unsigned short* zrow = zhl + (size_t)(row0 + sa_row) * 512;
    bool a_ok = (row0 + sa_row) < NN;
    int sb_col = t >> 1, sb_h = t & 1;           // B: 64B per thread
    const unsigned short* btrow = Bt + (size_t)sb_col * 768;

    for (int kt = 0; kt < 12; ++kt) {
        int ksb = kt * 64;
        int acol0 = (ksb & 255) + (ksb >= 512 ? 256 : 0);
        // stage A (swizzled: kgrp ^= row&7)
        uint4 av0 = make_uint4(0, 0, 0, 0), av1 = make_uint4(0, 0, 0, 0);
        if (a_ok) {
            av0 = *(const uint4*)(zrow + acol0 + sa_q * 16);
            av1 = *(const uint4*)(zrow + acol0 + sa_q * 16 + 8);
        }
        int rs = sa_row * 64;
        *(uint4*)&As[rs + ((2 * sa_q) ^ (sa_row & 7)) * 8] = av0;
        *(uint4*)&As[rs + ((2 * sa_q + 1) ^ (sa_row & 7)) * 8] = av1;
        // stage B
        const unsigned short* bsrc = btrow + ksb + sb_h * 32;
        int cs = sb_col * 64;
        #pragma unroll
        for (int j = 0; j < 4; ++j) {
            uint4 bv = *(const uint4*)(bsrc + j * 8);
            *(uint4*)&Bs[cs + ((sb_h * 4 + j) ^ (sb_col & 7)) * 8] = bv;
        }
        __syncthreads();
        #pragma unroll
        for (int s = 0; s < 2; ++s) {
            short8 af[4], bfr[4];
            #pragma unroll
            for (int fi = 0; fi < 4; ++fi) {
                int row = wm * 64 + fi * 16 + lr;
                int kg = (s * 4 + lk) ^ (row & 7);
                af[fi] = *(const short8*)&As[row * 64 + kg * 8];
            }
            #pragma unroll
            for (int bj = 0; bj < 4; ++bj) {
                int col = wn * 64 + bj * 16 + lr;
                int kg = (s * 4 + lk) ^ (col & 7);
                bfr[bj] = *(const short8*)&Bs[col * 64 + kg * 8];
            }
            #pragma unroll
            for (int fi = 0; fi < 4; ++fi)
                #pragma unroll
                for (int bj = 0; bj < 4; ++bj)
                    acc[fi][bj] = __builtin_amdgcn_mfma_f32_16x16x32_bf16(af[fi], bfr[bj], acc[fi][bj], 0, 0, 0);
        }
        __syncthreads();
    }

    // epilogue: store h2 + fused per-head logits (head == wn)
    float asr[4], adr[4];
    #pragma unroll
    for (int bj = 0; bj < 4; ++bj) {
        int cc = wn * 64 + bj * 16 + lr;
        asr[bj] = a_s[cc];
        adr[bj] = a_d[cc];
    }
    #pragma unroll
    for (int fi = 0; fi < 4; ++fi) {
        #pragma unroll
        for (int r = 0; r < 4; ++r) {
            int grow = row0 + wm * 64 + fi * 16 + lk * 4 + r;
            bool ok = grow < NN;
            float ps = 0.f, pd = 0.f;
            #pragma unroll
            for (int bj = 0; bj < 4; ++bj) {
                float vv = acc[fi][bj][r];
                if (ok) h2[(size_t)grow * HC + wn * 64 + bj * 16 + lr] = vv;
                ps += vv * asr[bj];
                pd += vv * adr[bj];
            }
            #pragma unroll
            for (int mm = 1; mm < 16; mm <<= 1) {
                ps += __shfl_xor(ps, mm, 64);
                pd += __shfl_xor(pd, mm, 64);
            }
            if (ok && lr == 0) {
                al_s[grow * 4 + wn] = ps;
                al_d[grow * 4 + wn] = pd;
            }
        }
    }
}

extern "C" void kernel_launch(void* const* d_in, const int* in_sizes, int n_in,
                              void* d_out, int out_size, void* d_ws, size_t ws_size,
                              hipStream_t stream) {
    const float* x   = (const float*)d_in[0];
    const int*   ei  = (const int*)d_in[1];
    const float* W1  = (const float*)d_in[2];
    const float* as1 = (const float*)d_in[3];
    const float* ad1 = (const float*)d_in[4];
    const float* b1  = (const float*)d_in[5];
    const float* W2  = (const float*)d_in[6];
    const float* as2 = (const float*)d_in[7];
    const float* ad2 = (const float*)d_in[8];
    const float* b2  = (const float*)d_in[9];
    const float* fcw = (const float*)d_in[10];
    const float* fcb = (const float*)d_in[11];
    float* out = (float*)d_out;

    char* p = (char*)d_ws;
    float* bufA = (float*)p; p += (size_t)NN * HC * 4;            // h1, later h2 (f32)
    unsigned short* zhl = (unsigned short*)p; p += (size_t)NN * 512 * 2;  // z1 bf16 hi|lo
    float* alS  = (float*)p; p += (size_t)NN * 4 * 4;
    float* alD  = (float*)p; p += (size_t)NN * 4 * 4;
    int* counts = (int*)p;   p += (size_t)NN * 4;                 // Bt aliases this later
    int* offs   = (int*)p;   p += (size_t)(NN + 1) * 4;
    int* cursor = (int*)p;   p += (size_t)NN * 4;
    int* csr    = (int*)p;   p += (size_t)NE * 4;
    int* partials = (int*)p; p += (size_t)NB_SCAN * 4;
    int* carries  = (int*)p; p += (size_t)NB_SCAN * 4;
    unsigned short* Bt = (unsigned short*)counts;  // 384KB, reused after scans

    const int* e_src = ei;
    const int* e_dst = ei + NE;

    hipMemsetAsync(counts, 0, NN * sizeof(int), stream);
    k_count<<<(NE + 255) / 256, 256, 0, stream>>>(e_dst, counts);
    k_scan1<<<NB_SCAN, 1024, 0, stream>>>(counts, offs, partials);
    k_scan2<<<1, 128, 0, stream>>>(partials, carries);
    k_scan3<<<NB_SCAN, 1024, 0, stream>>>(carries, offs, cursor);
    k_scatter<<<(NE + 255) / 256, 256, 0, stream>>>(e_src, e_dst, cursor, csr);
    k_prep_bt<<<768, 256, 0, stream>>>(W2, Bt);    // counts dead now

    k_gemm1<<<(NN + 3) / 4, 256, 0, stream>>>(x, W1, as1, ad1, bufA, alS, alD);
    k_agg<0><<<(NN + 3) / 4, 256, 0, stream>>>(bufA, alS, alD, offs, csr, b1,
                                               nullptr, nullptr, nullptr, zhl);
    k_gemm2_mfma<<<(NN + 127) / 128, 512, 0, stream>>>(zhl, Bt, as2, ad2, bufA, alS, alD);
    k_agg<1><<<(NN + 3) / 4, 256, 0, stream>>>(bufA, alS, alD, offs, csr, b2,
                                               fcw, fcb, out, nullptr);
}

// Round 3
// 531.437 us; speedup vs baseline: 2.3461x; 1.5203x over previous
//
#include <hip/hip_runtime.h>

#define NN 100000
#define NE 1600000
#define HC 256
#define NB_SCAN 98   // ceil(NN/1024)

typedef __attribute__((ext_vector_type(8))) short short8;
typedef __attribute__((ext_vector_type(4))) float f32x4;

__device__ __forceinline__ float4 ld4(const float* p) { return *(const float4*)p; }
__device__ __forceinline__ void st4(float* p, float4 v) { *(float4*)p = v; }
__device__ __forceinline__ unsigned short f2bf(float f) {
    unsigned u = __float_as_uint(f);
    return (unsigned short)((u + 0x7fffu + ((u >> 16) & 1u)) >> 16);
}
__device__ __forceinline__ float bf2f(unsigned short h) { return __uint_as_float(((unsigned)h) << 16); }

// ---------------- CSR build --------------------------------------------------
__global__ void k_count(const int* __restrict__ dst, int* __restrict__ counts) {
    int i = blockIdx.x * blockDim.x + threadIdx.x;
    if (i < NE) atomicAdd(&counts[dst[i]], 1);
}

__global__ void k_scan1(const int* __restrict__ counts, int* __restrict__ offs,
                        int* __restrict__ partials) {
    __shared__ int sh[1024];
    int b = blockIdx.x, t = threadIdx.x, i = b * 1024 + t;
    int v = (i < NN) ? counts[i] : 0;
    sh[t] = v;
    __syncthreads();
    for (int o = 1; o < 1024; o <<= 1) {
        int y = (t >= o) ? sh[t - o] : 0;
        __syncthreads();
        sh[t] += y;
        __syncthreads();
    }
    if (i < NN) offs[i] = sh[t] - v;
    if (t == 1023) partials[b] = sh[t];
}

__global__ void k_scan2(const int* __restrict__ partials, int* __restrict__ carries) {
    __shared__ int sh[128];
    int t = threadIdx.x;
    int v = (t < NB_SCAN) ? partials[t] : 0;
    sh[t] = v;
    __syncthreads();
    for (int o = 1; o < 128; o <<= 1) {
        int y = (t >= o) ? sh[t - o] : 0;
        __syncthreads();
        sh[t] += y;
        __syncthreads();
    }
    if (t < NB_SCAN) carries[t] = sh[t] - v;
}

__global__ void k_scan3(const int* __restrict__ carries, int* __restrict__ offs,
                        int* __restrict__ cursor) {
    int b = blockIdx.x, i = b * 1024 + threadIdx.x;
    if (i < NN) {
        int val = offs[i] + carries[b];
        offs[i] = val;
        cursor[i] = val;
    }
    if (i == 0) offs[NN] = NE;
}

__global__ void k_scatter(const int* __restrict__ src, const int* __restrict__ dst,
                          int* __restrict__ cursor, int* __restrict__ csr) {
    int i = blockIdx.x * blockDim.x + threadIdx.x;
    if (i < NE) {
        int d = dst[i];
        int p = atomicAdd(&cursor[d], 1);
        csr[p] = src[i];
    }
}

// ---------------- small precomputes ------------------------------------------
// ps1/pd1[h*4+k] = sum_c W1[k, h*64+c] * a1[h,c]   (k=0..2)
__global__ void k_prep_p1(const float* __restrict__ W1, const float* __restrict__ as1,
                          const float* __restrict__ ad1, float* __restrict__ ps1,
                          float* __restrict__ pd1) {
    int t = threadIdx.x;
    int h = t >> 6, cc = t & 63;
    float avs = as1[h * 64 + cc], avd = ad1[h * 64 + cc];
    for (int k = 0; k < 3; ++k) {
        float w = W1[k * 256 + h * 64 + cc];
        float vs = w * avs, vd = w * avd;
        #pragma unroll
        for (int m = 1; m < 64; m <<= 1) { vs += __shfl_xor(vs, m, 64); vd += __shfl_xor(vd, m, 64); }
        if (cc == 0) { ps1[h * 4 + k] = vs; pd1[h * 4 + k] = vd; }
    }
}

// u[h*256+k] = sum_c W2[k, h*64+c] * a2[h,c]
__global__ void k_prep_u2(const float* __restrict__ W2, const float* __restrict__ as2,
                          const float* __restrict__ ad2, float* __restrict__ u_s2,
                          float* __restrict__ u_d2) {
    int h = blockIdx.x & 3, sd = blockIdx.x >> 2;
    int k = threadIdx.x;
    const float* a = sd ? ad2 : as2;
    float sum = 0.f;
    for (int cc = 0; cc < 64; ++cc)
        sum += W2[(size_t)k * 256 + h * 64 + cc] * a[h * 64 + cc];
    (sd ? u_d2 : u_s2)[h * 256 + k] = sum;
}

// Bt[c][vk], vk: 0-255=hi(W2), 256-511=lo(W2), 512-767=hi(W2)
__global__ void k_prep_bt(const float* __restrict__ W2, unsigned short* __restrict__ Bt) {
    int vk = blockIdx.x, c = threadIdx.x;
    float v = W2[(size_t)(vk & 255) * HC + c];
    unsigned short hi = f2bf(v);
    unsigned short o = (vk < 256 || vk >= 512) ? hi : f2bf(v - bf2f(hi));
    Bt[(size_t)c * 768 + vk] = o;
}

// ---------------- layer-1 aggregation: recompute h1 from x on the fly --------
__global__ void k_agg1(const float* __restrict__ x, const float* __restrict__ W1,
                       const float* __restrict__ ps1, const float* __restrict__ pd1,
                       const int* __restrict__ offs, const int* __restrict__ csr,
                       const float* __restrict__ b1, const float* __restrict__ u_s2,
                       const float* __restrict__ u_d2, unsigned short* __restrict__ zhl,
                       float* __restrict__ alS2, float* __restrict__ alD2) {
    int d = (blockIdx.x * blockDim.x + threadIdx.x) >> 6;
    int lane = threadIdx.x & 63;
    if (d >= NN) return;
    int head = lane >> 4, c = lane << 2;
    float4 w0 = ld4(W1 + c), w1 = ld4(W1 + 256 + c), w2 = ld4(W1 + 512 + c);
    float psa = ps1[head * 4 + 0], psb = ps1[head * 4 + 1], psc = ps1[head * 4 + 2];
    float pda = pd1[head * 4 + 0], pdb = pd1[head * 4 + 1], pdc = pd1[head * 4 + 2];
    // self term
    float xd0 = x[d * 3], xd1 = x[d * 3 + 1], xd2 = x[d * 3 + 2];
    float ald = xd0 * pda + xd1 * pdb + xd2 * pdc;
    float e0 = xd0 * psa + xd1 * psb + xd2 * psc + ald;
    e0 = e0 > 0.f ? e0 : 0.2f * e0;
    float m = e0, s = 1.f;
    float4 acc;
    acc.x = xd0 * w0.x + xd1 * w1.x + xd2 * w2.x;
    acc.y = xd0 * w0.y + xd1 * w1.y + xd2 * w2.y;
    acc.z = xd0 * w0.z + xd1 * w1.z + xd2 * w2.z;
    acc.w = xd0 * w0.w + xd1 * w1.w + xd2 * w2.w;
    int beg = offs[d], end = offs[d + 1];
    for (int base = beg; base < end; base += 64) {
        int idx = base + lane;
        int bs = (idx < end) ? csr[idx] : 0;
        int b3 = bs * 3;
        float lx0 = x[b3], lx1 = x[b3 + 1], lx2 = x[b3 + 2];
        int cnt = min(64, end - base);
        for (int j = 0; j < cnt; ++j) {
            float x0 = __shfl(lx0, j, 64);
            float x1 = __shfl(lx1, j, 64);
            float x2 = __shfl(lx2, j, 64);
            float ev = x0 * psa + x1 * psb + x2 * psc + ald;
            ev = ev > 0.f ? ev : 0.2f * ev;
            float mn = fmaxf(m, ev);
            float cs = __expf(m - mn);
            float p = __expf(ev - mn);
            s = s * cs + p;
            acc.x = acc.x * cs + p * (x0 * w0.x + x1 * w1.x + x2 * w2.x);
            acc.y = acc.y * cs + p * (x0 * w0.y + x1 * w1.y + x2 * w2.y);
            acc.z = acc.z * cs + p * (x0 * w0.z + x1 * w1.z + x2 * w2.z);
            acc.w = acc.w * cs + p * (x0 * w0.w + x1 * w1.w + x2 * w2.w);
            m = mn;
        }
    }
    float inv = 1.f / (s + 1e-16f);
    float4 bv = ld4(b1 + c);
    float4 z;
    z.x = fmaxf(acc.x * inv + bv.x, 0.f);
    z.y = fmaxf(acc.y * inv + bv.y, 0.f);
    z.z = fmaxf(acc.z * inv + bv.z, 0.f);
    z.w = fmaxf(acc.w * inv + bv.w, 0.f);
    // write z1 as bf16 hi|lo for the MFMA GEMM
    ushort4 hi, lo;
    hi.x = f2bf(z.x); lo.x = f2bf(z.x - bf2f(hi.x));
    hi.y = f2bf(z.y); lo.y = f2bf(z.y - bf2f(hi.y));
    hi.z = f2bf(z.z); lo.z = f2bf(z.z - bf2f(hi.z));
    hi.w = f2bf(z.w); lo.w = f2bf(z.w - bf2f(hi.w));
    *(ushort4*)(zhl + (size_t)d * 512 + c) = hi;
    *(ushort4*)(zhl + (size_t)d * 512 + 256 + c) = lo;
    // exact layer-2 logits: al2[d,h] = z1[d] . u[h]
    #pragma unroll
    for (int h = 0; h < 4; ++h) {
        float4 us = ld4(u_s2 + h * 256 + c);
        float4 ud = ld4(u_d2 + h * 256 + c);
        float vs = z.x * us.x + z.y * us.y + z.z * us.z + z.w * us.w;
        float vd = z.x * ud.x + z.y * ud.y + z.z * ud.z + z.w * ud.w;
        #pragma unroll
        for (int mm = 1; mm < 64; mm <<= 1) { vs += __shfl_xor(vs, mm, 64); vd += __shfl_xor(vd, mm, 64); }
        if (lane == 0) { alS2[d * 4 + h] = vs; alD2[d * 4 + h] = vd; }
    }
}

// ---------------- GEMM2 via bf16 MFMA (hi/lo split), bf16 output -------------
__global__ __launch_bounds__(512) void k_gemm2_mfma(
    const unsigned short* __restrict__ zhl, const unsigned short* __restrict__ Bt,
    unsigned short* __restrict__ h2bf) {
    __shared__ __align__(16) unsigned short As[128 * 64];
    __shared__ __align__(16) unsigned short Bs[256 * 64];
    int t = threadIdx.x;
    int l = t & 63, w = t >> 6;
    int wm = w >> 2, wn = w & 3;
    int lr = l & 15, lk = l >> 4;
    int row0 = blockIdx.x * 128;

    f32x4 acc[4][4];
    f32x4 z4 = {0.f, 0.f, 0.f, 0.f};
    #pragma unroll
    for (int i = 0; i < 4; ++i)
        #pragma unroll
        for (int j = 0; j < 4; ++j) acc[i][j] = z4;

    int sa_row = t >> 2, sa_q = t & 3;
    const unsigned short* zrow = zhl + (size_t)(row0 + sa_row) * 512;
    bool a_ok = (row0 + sa_row) < NN;
    int sb_col = t >> 1, sb_h = t & 1;
    const unsigned short* btrow = Bt + (size_t)sb_col * 768;

    for (int kt = 0; kt < 12; ++kt) {
        int ksb = kt * 64;
        int acol0 = (ksb & 255) + (ksb >= 512 ? 256 : 0);
        uint4 av0 = make_uint4(0, 0, 0, 0), av1 = make_uint4(0, 0, 0, 0);
        if (a_ok) {
            av0 = *(const uint4*)(zrow + acol0 + sa_q * 16);
            av1 = *(const uint4*)(zrow + acol0 + sa_q * 16 + 8);
        }
        int rs = sa_row * 64;
        *(uint4*)&As[rs + ((2 * sa_q) ^ (sa_row & 7)) * 8] = av0;
        *(uint4*)&As[rs + ((2 * sa_q + 1) ^ (sa_row & 7)) * 8] = av1;
        const unsigned short* bsrc = btrow + ksb + sb_h * 32;
        int cs = sb_col * 64;
        #pragma unroll
        for (int j = 0; j < 4; ++j) {
            uint4 bv = *(const uint4*)(bsrc + j * 8);
            *(uint4*)&Bs[cs + ((sb_h * 4 + j) ^ (sb_col & 7)) * 8] = bv;
        }
        __syncthreads();
        #pragma unroll
        for (int s = 0; s < 2; ++s) {
            short8 af[4], bfr[4];
            #pragma unroll
            for (int fi = 0; fi < 4; ++fi) {
                int row = wm * 64 + fi * 16 + lr;
                int kg = (s * 4 + lk) ^ (row & 7);
                af[fi] = *(const short8*)&As[row * 64 + kg * 8];
            }
            #pragma unroll
            for (int bj = 0; bj < 4; ++bj) {
                int col = wn * 64 + bj * 16 + lr;
                int kg = (s * 4 + lk) ^ (col & 7);
                bfr[bj] = *(const short8*)&Bs[col * 64 + kg * 8];
            }
            #pragma unroll
            for (int fi = 0; fi < 4; ++fi)
                #pragma unroll
                for (int bj = 0; bj < 4; ++bj)
                    acc[fi][bj] = __builtin_amdgcn_mfma_f32_16x16x32_bf16(af[fi], bfr[bj], acc[fi][bj], 0, 0, 0);
        }
        __syncthreads();
    }

    #pragma unroll
    for (int fi = 0; fi < 4; ++fi) {
        #pragma unroll
        for (int r = 0; r < 4; ++r) {
            int grow = row0 + wm * 64 + fi * 16 + lk * 4 + r;
            if (grow < NN) {
                #pragma unroll
                for (int bj = 0; bj < 4; ++bj)
                    h2bf[(size_t)grow * HC + wn * 64 + bj * 16 + lr] = f2bf(acc[fi][bj][r]);
            }
        }
    }
}

// ---------------- layer-2 aggregation: gather bf16 h2 rows, fused fc ---------
__global__ void k_agg2(const unsigned short* __restrict__ h2bf, const float* __restrict__ alS2,
                       const float* __restrict__ alD2, const int* __restrict__ offs,
                       const int* __restrict__ csr, const float* __restrict__ b2,
                       const float* __restrict__ fcw, const float* __restrict__ fcb,
                       float* __restrict__ out) {
    int d = (blockIdx.x * blockDim.x + threadIdx.x) >> 6;
    int lane = threadIdx.x & 63;
    if (d >= NN) return;
    int head = lane >> 4;
    int c = lane << 2;
    float ald = alD2[d * 4 + head];
    float e0 = alS2[d * 4 + head] + ald;
    e0 = e0 > 0.f ? e0 : 0.2f * e0;
    float m = e0, s = 1.f;
    ushort4 hs = *(const ushort4*)(h2bf + (size_t)d * HC + c);
    float4 acc;
    acc.x = bf2f(hs.x); acc.y = bf2f(hs.y); acc.z = bf2f(hs.z); acc.w = bf2f(hs.w);
    int beg = offs[d], end = offs[d + 1];
    if (beg < end) {
        int sn = csr[beg];
        float asv = alS2[sn * 4 + head];
        ushort4 hv = *(const ushort4*)(h2bf + (size_t)sn * HC + c);
        for (int i = beg; i < end; ++i) {
            int i2 = i + 1;
            int sn2 = (i2 < end) ? csr[i2] : sn;
            float as2 = alS2[sn2 * 4 + head];
            ushort4 hv2 = *(const ushort4*)(h2bf + (size_t)sn2 * HC + c);
            float ev = asv + ald;
            ev = ev > 0.f ? ev : 0.2f * ev;
            float mn = fmaxf(m, ev);
            float cs = __expf(m - mn);
            float p = __expf(ev - mn);
            s = s * cs + p;
            acc.x = acc.x * cs + p * bf2f(hv.x);
            acc.y = acc.y * cs + p * bf2f(hv.y);
            acc.z = acc.z * cs + p * bf2f(hv.z);
            acc.w = acc.w * cs + p * bf2f(hv.w);
            m = mn;
            sn = sn2; asv = as2; hv = hv2;
        }
    }
    float inv = 1.f / (s + 1e-16f);
    float4 bv = ld4(b2 + c);
    float4 o;
    o.x = fmaxf(acc.x * inv + bv.x, 0.f);
    o.y = fmaxf(acc.y * inv + bv.y, 0.f);
    o.z = fmaxf(acc.z * inv + bv.z, 0.f);
    o.w = fmaxf(acc.w * inv + bv.w, 0.f);
    float4 f0 = ld4(fcw + c * 2);       // {w[c][0],w[c][1],w[c+1][0],w[c+1][1]}
    float4 f1 = ld4(fcw + c * 2 + 4);
    float p0 = o.x * f0.x + o.y * f0.z + o.z * f1.x + o.w * f1.z;
    float p1 = o.x * f0.y + o.y * f0.w + o.z * f1.y + o.w * f1.w;
    #pragma unroll
    for (int mm = 1; mm < 64; mm <<= 1) {
        p0 += __shfl_xor(p0, mm, 64);
        p1 += __shfl_xor(p1, mm, 64);
    }
    if (lane == 0) {
        out[d * 2 + 0] = p0 + fcb[0];
        out[d * 2 + 1] = p1 + fcb[1];
    }
}

extern "C" void kernel_launch(void* const* d_in, const int* in_sizes, int n_in,
                              void* d_out, int out_size, void* d_ws, size_t ws_size,
                              hipStream_t stream) {
    const float* x   = (const float*)d_in[0];
    const int*   ei  = (const int*)d_in[1];
    const float* W1  = (const float*)d_in[2];
    const float* as1 = (const float*)d_in[3];
    const float* ad1 = (const float*)d_in[4];
    const float* b1  = (const float*)d_in[5];
    const float* W2  = (const float*)d_in[6];
    const float* as2 = (const float*)d_in[7];
    const float* ad2 = (const float*)d_in[8];
    const float* b2  = (const float*)d_in[9];
    const float* fcw = (const float*)d_in[10];
    const float* fcb = (const float*)d_in[11];
    float* out = (float*)d_out;

    char* p = (char*)d_ws;
    unsigned short* zhl  = (unsigned short*)p; p += (size_t)NN * 512 * 2;  // 102.4MB
    unsigned short* h2bf = (unsigned short*)p; p += (size_t)NN * 256 * 2;  // 51.2MB
    float* alS2 = (float*)p; p += (size_t)NN * 4 * 4;
    float* alD2 = (float*)p; p += (size_t)NN * 4 * 4;
    float* ps1  = (float*)p; p += 256;
    float* pd1  = (float*)p; p += 256;
    float* u_s2 = (float*)p; p += 4 * 256 * 4;
    float* u_d2 = (float*)p; p += 4 * 256 * 4;
    int* counts = (int*)p;   p += (size_t)NN * 4;      // Bt aliases this (384KB < 400KB)
    int* offs   = (int*)p;   p += (size_t)(NN + 2) * 4;
    int* cursor = (int*)p;   p += (size_t)NN * 4;
    int* csr    = (int*)p;   p += (size_t)NE * 4;
    int* partials = (int*)p; p += 512;
    int* carries  = (int*)p; p += 512;
    unsigned short* Bt = (unsigned short*)counts;

    const int* e_src = ei;
    const int* e_dst = ei + NE;

    hipMemsetAsync(counts, 0, NN * sizeof(int), stream);
    k_count<<<(NE + 255) / 256, 256, 0, stream>>>(e_dst, counts);
    k_scan1<<<NB_SCAN, 1024, 0, stream>>>(counts, offs, partials);
    k_scan2<<<1, 128, 0, stream>>>(partials, carries);
    k_scan3<<<NB_SCAN, 1024, 0, stream>>>(carries, offs, cursor);
    k_scatter<<<(NE + 255) / 256, 256, 0, stream>>>(e_src, e_dst, cursor, csr);

    k_prep_bt<<<768, 256, 0, stream>>>(W2, Bt);   // counts dead after scan1
    k_prep_p1<<<1, 256, 0, stream>>>(W1, as1, ad1, ps1, pd1);
    k_prep_u2<<<8, 256, 0, stream>>>(W2, as2, ad2, u_s2, u_d2);

    k_agg1<<<(NN + 3) / 4, 256, 0, stream>>>(x, W1, ps1, pd1, offs, csr, b1,
                                             u_s2, u_d2, zhl, alS2, alD2);
    k_gemm2_mfma<<<(NN + 127) / 128, 512, 0, stream>>>(zhl, Bt, h2bf);
    k_agg2<<<(NN + 3) / 4, 256, 0, stream>>>(h2bf, alS2, alD2, offs, csr, b2,
                                             fcw, fcb, out);
}